// Round 6
// baseline (579.281 us; speedup 1.0000x reference)
//
#include <hip/hip_runtime.h>

typedef __attribute__((ext_vector_type(4))) short short4v;
typedef __attribute__((ext_vector_type(8))) short short8;
typedef __attribute__((ext_vector_type(4))) float floatx4;

#define NB 16384
#define TT 24
#define HH 128
#define LDA 40    // As row stride (u16); 80 B, 16B-aligned rows
#define LDH 136   // h row stride (u16); 272 B, 16B-aligned rows
#define ASZ (64 * LDA)
#define HSZ (64 * LDH)

__device__ __forceinline__ float bf2f(unsigned short u) {
    union { unsigned int i; float f; } v; v.i = ((unsigned int)u) << 16; return v.f;
}
__device__ __forceinline__ unsigned short f2bf(float f) {
    union { float f; unsigned int i; } v; v.f = f;
    unsigned int x = v.i;
    return (unsigned short)((x + 0x7fffu + ((x >> 16) & 1u)) >> 16);
}
__device__ __forceinline__ float fsig(float x) {
    return __fdividef(1.f, 1.f + __expf(-x));
}
__device__ __forceinline__ float ftanh(float x) {
    x = fminf(15.f, fmaxf(-15.f, x));
    float e = __expf(2.f * x);
    return __fdividef(e - 1.f, e + 1.f);
}
__device__ __forceinline__ short4v pk4(floatx4 a) {
    short4v r;
    r[0] = (short)f2bf(a[0]); r[1] = (short)f2bf(a[1]);
    r[2] = (short)f2bf(a[2]); r[3] = (short)f2bf(a[3]);
    return r;
}
// swizzled h-LDS address (u16 units): 16B chunk index XOR'd with row bit3.
__device__ __forceinline__ int haddr(int row, int k) {
    int chunk = (k >> 3) ^ ((row & 8) >> 2);
    return row * LDH + (chunk << 3) + (k & 7);
}

// ---- k_prep: convert f32 weights to packed bf16 in ws (1.18 MB).
__global__ void k_prep(const float* __restrict__ W_ih, const float* __restrict__ W_dh,
                       const float* __restrict__ W_hh, const float* __restrict__ W_mu,
                       const float* __restrict__ W_std, unsigned short* __restrict__ Wc,
                       unsigned short* __restrict__ Whh, unsigned short* __restrict__ Wms) {
    int blk = blockIdx.x;
    if (blk < 512) {
        const float* src = (blk < 384) ? (W_ih + (size_t)blk * 1060)
                                       : (W_dh + (size_t)(blk - 384) * 1056);
        unsigned short* dst = Wc + (size_t)blk * 1056;
        for (int k = threadIdx.x; k < 1056; k += 256) dst[k] = f2bf(src[k]);
    } else if (blk < 896) {
        int r = blk - 512;
        if (threadIdx.x < 128) Whh[r * 128 + threadIdx.x] = f2bf(W_hh[r * 128 + threadIdx.x]);
    } else {
        for (int i = threadIdx.x; i < 512; i += 256) {
            int r = i >> 7, k = i & 127;
            Wms[i] = f2bf(r < 2 ? W_mu[r * 128 + k] : W_std[(r - 2) * 128 + k]);
        }
    }
}

// ---- fused decoder: 256 blocks x 512 threads; block owns 64 batch rows.
// NOTE: __launch_bounds__(512) only — the (512,2) variant made the allocator
// cap arch VGPRs and SPILL in the 24-step loop (R5: WRITE_SIZE 6.1->15.4 MB).
__global__ __launch_bounds__(512) void k_fused(
    const float* __restrict__ last, const float* __restrict__ enc,
    const float* __restrict__ zin, const float* __restrict__ sg,
    const float* __restrict__ fut, const float* __restrict__ b_dh,
    const float* __restrict__ W_vel, const float* __restrict__ b_vel,
    const float* __restrict__ W_ih, const float* __restrict__ b_ih,
    const float* __restrict__ b_hh, const float* __restrict__ b_mu,
    const float* __restrict__ b_std, const unsigned short* __restrict__ Wc,
    const unsigned short* __restrict__ Whh, const unsigned short* __restrict__ Wms,
    float* __restrict__ out) {
    __shared__ unsigned short As[2 * ASZ];
    __shared__ unsigned short h2[2 * HSZ];
    __shared__ float a_lds[2][64][2];
    __shared__ float rel_lds[64][2];

    const int tid = threadIdx.x;
    const int w = tid >> 6, lane = tid & 63;
    const int col = lane & 15, q = lane >> 4;
    const int b0 = blockIdx.x * 64;
    const int jc = w * 16 + col;

    // a0 = last_obs @ W_vel.T + b_vel ; rel = (sg - last[:, :2]) / 4.8
    if (tid < 128) {
        int row = tid >> 1, c = tid & 1;
        int b = b0 + row;
        float s = b_vel[c];
#pragma unroll
        for (int s2 = 0; s2 < 6; s2++) s += last[b * 6 + s2] * W_vel[c * 6 + s2];
        a_lds[0][row][c] = s;
        rel_lds[row][c] = (sg[b * 2 + c] - last[b * 6 + c]) * (1.f / 4.8f);
    }

    // ---------------- phase 1: K=1056 GEMM into registers ----------------
    floatx4 acc2[4][4];  // [mt][gg]: gg 0..2 gates, gg=3 -> h0
#pragma unroll
    for (int i = 0; i < 4; i++)
#pragma unroll
        for (int j = 0; j < 4; j++) acc2[i][j] = (floatx4){0.f, 0.f, 0.f, 0.f};

    const int arow = tid >> 3, koff = (tid & 7) * 4;

    {
        floatx4 a0 = *(const floatx4*)(enc + (size_t)(b0 + arow) * 1024 + koff);
        *(short4v*)(As + arow * LDA + koff) = pk4(a0);
    }
    __syncthreads();

    for (int ki = 0; ki < 33; ki++) {
        const int cur = ki & 1, nxt = cur ^ 1;
        floatx4 an;
        if (ki < 32) {
            an = (ki + 1 < 32)
                ? *(const floatx4*)(enc + (size_t)(b0 + arow) * 1024 + (ki + 1) * 32 + koff)
                : *(const floatx4*)(zin + (size_t)(b0 + arow) * 32 + koff);
        }
        short8 bb[4];
#pragma unroll
        for (int gg = 0; gg < 4; gg++)
            bb[gg] = *(const short8*)(Wc + (size_t)(gg * 128 + jc) * 1056 + ki * 32 + q * 8);
        short8 af[4];
#pragma unroll
        for (int mt = 0; mt < 4; mt++)
            af[mt] = *(const short8*)(As + cur * ASZ + (mt * 16 + col) * LDA + q * 8);
#pragma unroll
        for (int gg = 0; gg < 4; gg++)
#pragma unroll
            for (int mt = 0; mt < 4; mt++)
                acc2[mt][gg] = __builtin_amdgcn_mfma_f32_16x16x32_bf16(
                    af[mt], bb[gg], acc2[mt][gg], 0, 0, 0);
        if (ki < 32) *(short4v*)(As + nxt * ASZ + arow * LDA + koff) = pk4(an);
        __syncthreads();
    }

    // phase-1 epilogue -> greg / hprev registers, h0 -> h2 buf0 (bf16, swizzled)
    float bihg[3], wr0g[3], wr1g[3], wa0[3], wa1[3], bhh_n;
#pragma unroll
    for (int g = 0; g < 3; g++) {
        const size_t rb = (size_t)(g * HH + jc) * 1060;
        bihg[g] = b_ih[g * HH + jc] + ((g < 2) ? b_hh[g * HH + jc] : 0.f);
        wa0[g] = W_ih[rb + 1056];
        wa1[g] = W_ih[rb + 1057];
        wr0g[g] = W_ih[rb + 1058];
        wr1g[g] = W_ih[rb + 1059];
    }
    bhh_n = b_hh[2 * HH + jc];

    float greg[4][3][4];
    float hprev[4][4];
    const float bdh = b_dh[jc];
#pragma unroll
    for (int mt = 0; mt < 4; mt++) {
#pragma unroll
        for (int r = 0; r < 4; r++) {
            int blr = mt * 16 + q * 4 + r;
            float r0 = rel_lds[blr][0], r1 = rel_lds[blr][1];
#pragma unroll
            for (int g = 0; g < 3; g++)
                greg[mt][g][r] = acc2[mt][g][r] + bihg[g] + r0 * wr0g[g] + r1 * wr1g[g];
            float h0v = acc2[mt][3][r] + bdh;
            hprev[mt][r] = h0v;
            h2[haddr(blr, jc)] = f2bf(h0v);
        }
    }

    // resident W_hh fragments (48 VGPR — the one big resident block we keep)
    short8 bfr[3][4];
#pragma unroll
    for (int g = 0; g < 3; g++)
#pragma unroll
        for (int kt = 0; kt < 4; kt++)
            bfr[g][kt] = *(const short8*)(Whh + (size_t)(g * HH + jc) * HH + kt * 32 + q * 8);

    float msbias = 0.f;
    if (w < 2 && col < 4) msbias = (col >= 2) ? b_std[col & 1] : b_mu[col & 1];

    // opaque pointer: forces per-step reload of ms fragments (defeats LICM so the
    // 16 VGPRs of msf are NOT live across the whole t-loop -> no spill)
    const unsigned short* wms_p = Wms;

    __syncthreads();  // h0 visible

    // ---------------- phase 2: 24-step recurrence, 1 barrier/step ----------------
    for (int t = 0; t < TT; t++) {
        const unsigned short* hc = h2 + (t & 1) * HSZ;
        unsigned short* hn = h2 + ((t + 1) & 1) * HSZ;

        asm volatile("" : "+v"(wms_p));  // opaque each iteration

        floatx4 acc[4][3];
        floatx4 accms[2];
#pragma unroll
        for (int mt = 0; mt < 4; mt++)
#pragma unroll
            for (int g = 0; g < 3; g++) acc[mt][g] = (floatx4){0.f, 0.f, 0.f, 0.f};
        accms[0] = (floatx4){0.f, 0.f, 0.f, 0.f};
        accms[1] = (floatx4){0.f, 0.f, 0.f, 0.f};

        short8 msf[4];
        if (w < 2 && t > 0) {
#pragma unroll
            for (int kt = 0; kt < 4; kt++)
                msf[kt] = (col < 4) ? *(const short8*)(wms_p + col * 128 + kt * 32 + q * 8)
                                    : (short8){0, 0, 0, 0, 0, 0, 0, 0};
        }

#pragma unroll
        for (int kt = 0; kt < 4; kt++) {
            short8 af2[4];
#pragma unroll
            for (int mt = 0; mt < 4; mt++)
                af2[mt] = *(const short8*)(hc + haddr(mt * 16 + col, kt * 32 + q * 8));
#pragma unroll
            for (int mt = 0; mt < 4; mt++)
#pragma unroll
                for (int g = 0; g < 3; g++)
                    acc[mt][g] = __builtin_amdgcn_mfma_f32_16x16x32_bf16(
                        af2[mt], bfr[g][kt], acc[mt][g], 0, 0, 0);
            if (w < 2 && t > 0) {
#pragma unroll
                for (int mtl = 0; mtl < 2; mtl++)
                    accms[mtl] = __builtin_amdgcn_mfma_f32_16x16x32_bf16(
                        af2[w * 2 + mtl], msf[kt], accms[mtl], 0, 0, 0);
            }
        }

        // mu/std for h_t (t>=1) -> out row t-1
        if (w < 2 && t > 0 && col < 4) {
            int kind = col >> 1, c = col & 1;
#pragma unroll
            for (int mtl = 0; mtl < 2; mtl++)
#pragma unroll
                for (int r = 0; r < 4; r++) {
                    float val = accms[mtl][r] + msbias;
                    if (kind) val = __expf(0.5f * val);
                    int b = b0 + (w * 2 + mtl) * 16 + q * 4 + r;
                    out[(size_t)kind * (TT * NB * 2) + (size_t)(t - 1) * NB * 2 + b * 2 + c] = val;
                }
        }

        // gates
#pragma unroll
        for (int mt = 0; mt < 4; mt++) {
#pragma unroll
            for (int r = 0; r < 4; r++) {
                int blr = mt * 16 + q * 4 + r;
                float a0v = a_lds[t & 1][blr][0], a1v = a_lds[t & 1][blr][1];
                float gir = greg[mt][0][r] + a0v * wa0[0] + a1v * wa1[0] + acc[mt][0][r];
                float giz = greg[mt][1][r] + a0v * wa0[1] + a1v * wa1[1] + acc[mt][1][r];
                float gin = greg[mt][2][r] + a0v * wa0[2] + a1v * wa1[2];
                float ghn = acc[mt][2][r] + bhh_n;
                float rg = fsig(gir);
                float zg = fsig(giz);
                float ng = ftanh(gin + rg * ghn);
                hprev[mt][r] = (1.f - zg) * ng + zg * hprev[mt][r];
            }
        }

        // write h_{t+1} into the other buffer; waves 6-7 stage next a
#pragma unroll
        for (int mt = 0; mt < 4; mt++)
#pragma unroll
            for (int r = 0; r < 4; r++)
                hn[haddr(mt * 16 + q * 4 + r, jc)] = f2bf(hprev[mt][r]);
        if (tid >= 384) {
            int row = (tid - 384) >> 1, c = tid & 1;
            a_lds[(t + 1) & 1][row][c] = fut[((size_t)t * NB + b0 + row) * 6 + 2 + c];
        }

        __syncthreads();
    }

    // final mu/std pass for h_TT -> out row TT-1  (h_TT lives in buf TT&1 = 0)
    if (w < 2) {
        const unsigned short* hc = h2 + (TT & 1) * HSZ;
        floatx4 accms[2];
        accms[0] = (floatx4){0.f, 0.f, 0.f, 0.f};
        accms[1] = (floatx4){0.f, 0.f, 0.f, 0.f};
#pragma unroll
        for (int kt = 0; kt < 4; kt++) {
            short8 msf = (col < 4) ? *(const short8*)(wms_p + col * 128 + kt * 32 + q * 8)
                                   : (short8){0, 0, 0, 0, 0, 0, 0, 0};
#pragma unroll
            for (int mtl = 0; mtl < 2; mtl++) {
                short8 af2 = *(const short8*)(hc + haddr((w * 2 + mtl) * 16 + col, kt * 32 + q * 8));
                accms[mtl] = __builtin_amdgcn_mfma_f32_16x16x32_bf16(
                    af2, msf, accms[mtl], 0, 0, 0);
            }
        }
        if (col < 4) {
            int kind = col >> 1, c = col & 1;
#pragma unroll
            for (int mtl = 0; mtl < 2; mtl++)
#pragma unroll
                for (int r = 0; r < 4; r++) {
                    float val = accms[mtl][r] + msbias;
                    if (kind) val = __expf(0.5f * val);
                    int b = b0 + (w * 2 + mtl) * 16 + q * 4 + r;
                    out[(size_t)kind * (TT * NB * 2) + (size_t)(TT - 1) * NB * 2 + b * 2 + c] = val;
                }
        }
    }
}

extern "C" void kernel_launch(void* const* d_in, const int* in_sizes, int n_in,
                              void* d_out, int out_size, void* d_ws, size_t ws_size,
                              hipStream_t stream) {
    (void)in_sizes; (void)n_in; (void)out_size; (void)ws_size;
    const float* last  = (const float*)d_in[0];
    const float* enc   = (const float*)d_in[1];
    const float* zin   = (const float*)d_in[2];
    const float* sg    = (const float*)d_in[3];
    const float* fut   = (const float*)d_in[4];
    const float* W_dh  = (const float*)d_in[5];
    const float* b_dh  = (const float*)d_in[6];
    const float* W_vel = (const float*)d_in[7];
    const float* b_vel = (const float*)d_in[8];
    const float* W_ih  = (const float*)d_in[9];
    const float* b_ih  = (const float*)d_in[10];
    const float* W_hh  = (const float*)d_in[11];
    const float* b_hh  = (const float*)d_in[12];
    const float* W_mu  = (const float*)d_in[13];
    const float* b_mu  = (const float*)d_in[14];
    const float* W_std = (const float*)d_in[15];
    const float* b_std = (const float*)d_in[16];
    float* out = (float*)d_out;

    char* ws = (char*)d_ws;
    unsigned short* Wc  = (unsigned short*)ws;              // 512*1056*2 = 1,081,344 B
    unsigned short* Whh = (unsigned short*)(ws + 1081344);  // 384*128*2  =    98,304 B
    unsigned short* Wms = (unsigned short*)(ws + 1179648);  // 4*128*2    =     1,024 B

    k_prep<<<897, 256, 0, stream>>>(W_ih, W_dh, W_hh, W_mu, W_std, Wc, Whh, Wms);
    k_fused<<<256, 512, 0, stream>>>(last, enc, zin, sg, fut, b_dh, W_vel, b_vel,
                                     W_ih, b_ih, b_hh, b_mu, b_std, Wc, Whh, Wms, out);
}

// Round 7
// 339.234 us; speedup vs baseline: 1.7076x; 1.7076x over previous
//
#include <hip/hip_runtime.h>

typedef __attribute__((ext_vector_type(4))) short short4v;
typedef __attribute__((ext_vector_type(8))) short short8;
typedef __attribute__((ext_vector_type(4))) float floatx4;

#define NB 16384
#define TT 24
#define HH 128
#define LDA 40    // As row stride (u16)
#define LDH 168   // h row stride (u16): 160 K-ext cols + 8 pad
#define ASZ (32 * LDA)
#define HSZ (32 * LDH)
#define MUS_OFF 0
#define STD_OFF (TT * NB * 2)

__device__ __forceinline__ float bf2f(unsigned short u) {
    union { unsigned int i; float f; } v; v.i = ((unsigned int)u) << 16; return v.f;
}
__device__ __forceinline__ unsigned short f2bf(float f) {
    union { float f; unsigned int i; } v; v.f = f;
    unsigned int x = v.i;
    return (unsigned short)((x + 0x7fffu + ((x >> 16) & 1u)) >> 16);
}
__device__ __forceinline__ float fsig(float x) {
    return __fdividef(1.f, 1.f + __expf(-x));
}
__device__ __forceinline__ float ftanh(float x) {
    x = fminf(15.f, fmaxf(-15.f, x));
    float e = __expf(2.f * x);
    return __fdividef(e - 1.f, e + 1.f);
}
__device__ __forceinline__ short4v pk4(floatx4 a) {
    short4v r;
    r[0] = (short)f2bf(a[0]); r[1] = (short)f2bf(a[1]);
    r[2] = (short)f2bf(a[2]); r[3] = (short)f2bf(a[3]);
    return r;
}
__device__ __forceinline__ unsigned int pk2(float a, float b) {
    return (unsigned int)f2bf(a) | ((unsigned int)f2bf(b) << 16);
}
__device__ __forceinline__ float upk(unsigned int u, int hi) {
    union { unsigned int i; float f; } v;
    v.i = hi ? (u & 0xffff0000u) : (u << 16);
    return v.f;
}

// ---- k_prep: pack weights bf16 into ws.
// Wc  : 512 x 1056 (rows 0..383 = W_ih[:, :1056], 384..511 = W_dh)
// Whh : 384 x 160  K-extended: [0..127]=W_hh row; g<2: [128]=wa0,[129]=wa1;
//       g==2: [130]=b_hh_n; rest 0.
// Wms : 4 x 128 (mu0, mu1, std0, std1)
__global__ void k_prep(const float* __restrict__ W_ih, const float* __restrict__ W_dh,
                       const float* __restrict__ W_hh, const float* __restrict__ b_hh,
                       const float* __restrict__ W_mu, const float* __restrict__ W_std,
                       unsigned short* __restrict__ Wc, unsigned short* __restrict__ Whh,
                       unsigned short* __restrict__ Wms) {
    int blk = blockIdx.x, t = threadIdx.x;
    if (blk < 512) {
        const float* src = (blk < 384) ? (W_ih + (size_t)blk * 1060)
                                       : (W_dh + (size_t)(blk - 384) * 1056);
        unsigned short* dst = Wc + (size_t)blk * 1056;
        for (int k = t; k < 1056; k += 256) dst[k] = f2bf(src[k]);
    } else if (blk < 896) {
        int r = blk - 512;              // g*128 + jc
        int g = r >> 7;
        unsigned short* dst = Whh + (size_t)r * 160;
        if (t < 128) dst[t] = f2bf(W_hh[(size_t)r * 128 + t]);
        else if (t == 128) dst[128] = (g < 2) ? f2bf(W_ih[(size_t)r * 1060 + 1056]) : 0;
        else if (t == 129) dst[129] = (g < 2) ? f2bf(W_ih[(size_t)r * 1060 + 1057]) : 0;
        else if (t == 130) dst[130] = (g == 2) ? f2bf(b_hh[r]) : 0;
        else if (t < 160) dst[t] = 0;
    } else {
        for (int i = t; i < 512; i += 256) {
            int r = i >> 7, k = i & 127;
            Wms[i] = f2bf(r < 2 ? W_mu[r * 128 + k] : W_std[(r - 2) * 128 + k]);
        }
    }
}

// ---- fused decoder: 512 blocks x 512 threads; block owns 32 batch rows;
// 2 blocks/CU (4 waves/SIMD) is the point of this layout.
__global__ __launch_bounds__(512, 4) void k_fused(
    const float* __restrict__ last, const float* __restrict__ enc,
    const float* __restrict__ zin, const float* __restrict__ sg,
    const float* __restrict__ fut, const float* __restrict__ b_dh,
    const float* __restrict__ W_vel, const float* __restrict__ b_vel,
    const float* __restrict__ W_ih, const float* __restrict__ b_ih,
    const float* __restrict__ b_hh, const float* __restrict__ b_mu,
    const float* __restrict__ b_std, const unsigned short* __restrict__ Wc,
    const unsigned short* __restrict__ Whh, const unsigned short* __restrict__ Wms,
    float* __restrict__ out) {
    __shared__ unsigned short As[2 * ASZ];
    __shared__ unsigned short h2[2 * HSZ];
    __shared__ unsigned short wms_lds[512];
    __shared__ float rel_lds[32][2];

    const int tid = threadIdx.x;
    const int w = tid >> 6, lane = tid & 63;
    const int col = lane & 15, q = lane >> 4;
    const int b0 = blockIdx.x * 32;
    const int jc = w * 16 + col;

    // epilogue role constants: 128 tasks x 4 threads (k-quarters)
    const int etask = tid >> 2, epart = tid & 3;
    const int erow = etask >> 2, ekind = (etask >> 1) & 1, ec = etask & 1;
    const float ebias = ekind ? b_std[ec] : b_mu[ec];

    // stage wms (bf16 copy)
    if (tid < 512) wms_lds[tid] = Wms[tid];
    // const-fill h ext slots (k=128..159) of both buffers; skip buf0 k=128,129
    for (int i = tid; i < 2 * 32 * 32; i += 512) {
        int buf = i >> 10, loc = i & 1023, row = loc >> 5, kk = loc & 31;
        if (buf == 0 && kk < 2) continue;  // a0 written below by tid<64
        h2[buf * HSZ + row * LDH + 128 + kk] = (kk == 2) ? (unsigned short)0x3F80 : 0;
    }
    // a0 = last @ W_vel.T + b_vel -> buf0 ext slots; rel -> rel_lds
    if (tid < 64) {
        int row = tid >> 1, c = tid & 1, b = b0 + row;
        float s = b_vel[c];
#pragma unroll
        for (int s2 = 0; s2 < 6; s2++) s += last[b * 6 + s2] * W_vel[c * 6 + s2];
        h2[row * LDH + 128 + c] = f2bf(s);
        rel_lds[row][c] = (sg[b * 2 + c] - last[b * 6 + c]) * (1.f / 4.8f);
    }

    // ---------------- phase 1: K=1056 GEMM into registers ----------------
    floatx4 acc2[2][4];
#pragma unroll
    for (int i = 0; i < 2; i++)
#pragma unroll
        for (int j = 0; j < 4; j++) acc2[i][j] = (floatx4){0.f, 0.f, 0.f, 0.f};

    const int arow = tid >> 3, koff = (tid & 7) * 4;  // tid<256 stage 32x32
    if (tid < 256) {
        floatx4 a0 = *(const floatx4*)(enc + (size_t)(b0 + arow) * 1024 + koff);
        *(short4v*)(As + arow * LDA + koff) = pk4(a0);
    }
    __syncthreads();

    for (int ki = 0; ki < 33; ki++) {
        const int cur = ki & 1;
        floatx4 an;
        if (tid < 256 && ki < 32) {
            an = (ki + 1 < 32)
                ? *(const floatx4*)(enc + (size_t)(b0 + arow) * 1024 + (ki + 1) * 32 + koff)
                : *(const floatx4*)(zin + (size_t)(b0 + arow) * 32 + koff);
        }
        short8 bb[4];
#pragma unroll
        for (int gg = 0; gg < 4; gg++)
            bb[gg] = *(const short8*)(Wc + (size_t)(gg * 128 + jc) * 1056 + ki * 32 + q * 8);
        short8 af[2];
#pragma unroll
        for (int mt = 0; mt < 2; mt++)
            af[mt] = *(const short8*)(As + cur * ASZ + (mt * 16 + col) * LDA + q * 8);
#pragma unroll
        for (int gg = 0; gg < 4; gg++)
#pragma unroll
            for (int mt = 0; mt < 2; mt++)
                acc2[mt][gg] = __builtin_amdgcn_mfma_f32_16x16x32_bf16(
                    af[mt], bb[gg], acc2[mt][gg], 0, 0, 0);
        if (tid < 256 && ki < 32) *(short4v*)(As + (cur ^ 1) * ASZ + arow * LDA + koff) = pk4(an);
        __syncthreads();
    }

    // phase-1 epilogue: greg (packed bf16 pairs), hprev, h0 -> buf0
    unsigned int gp[2][3][2];  // [mt][gate][r-pair]
    float hprev[2][4];
    {
        float bihg[3], wr0g[3], wr1g[3];
#pragma unroll
        for (int g = 0; g < 3; g++) {
            const size_t rb = (size_t)(g * HH + jc) * 1060;
            bihg[g] = b_ih[g * HH + jc] + ((g < 2) ? b_hh[g * HH + jc] : 0.f);
            wr0g[g] = W_ih[rb + 1058];
            wr1g[g] = W_ih[rb + 1059];
        }
        const float bdh = b_dh[jc];
#pragma unroll
        for (int mt = 0; mt < 2; mt++) {
            float gv[3][4];
#pragma unroll
            for (int r = 0; r < 4; r++) {
                int row = mt * 16 + q * 4 + r;
                float r0 = rel_lds[row][0], r1 = rel_lds[row][1];
#pragma unroll
                for (int g = 0; g < 3; g++)
                    gv[g][r] = acc2[mt][g][r] + bihg[g] + r0 * wr0g[g] + r1 * wr1g[g];
                float h0v = acc2[mt][3][r] + bdh;
                hprev[mt][r] = h0v;
                h2[row * LDH + jc] = f2bf(h0v);
            }
#pragma unroll
            for (int g = 0; g < 3; g++) {
                gp[mt][g][0] = pk2(gv[g][0], gv[g][1]);
                gp[mt][g][1] = pk2(gv[g][2], gv[g][3]);
            }
        }
    }

    // resident W_hh fragments for kt=0..3 (48 VGPR)
    short8 bfr[3][4];
#pragma unroll
    for (int g = 0; g < 3; g++)
#pragma unroll
        for (int kt = 0; kt < 4; kt++)
            bfr[g][kt] = *(const short8*)(Whh + (size_t)(g * HH + jc) * 160 + kt * 32 + q * 8);
    // n-gate a-weights (VALU path; must not be scaled by r)
    const float wan0 = W_ih[(size_t)(2 * HH + jc) * 1060 + 1056];
    const float wan1 = W_ih[(size_t)(2 * HH + jc) * 1060 + 1057];

    __syncthreads();  // h0 + a0 + ext slots visible

    // ---------------- phase 2: 24 steps, 1 barrier/step ----------------
    for (int t = 0; t < TT; t++) {
        const unsigned short* hc = h2 + (t & 1) * HSZ;
        unsigned short* hn = h2 + ((t + 1) & 1) * HSZ;

        // ---- mu/std epilogue for h_t (t>=1) -> out row t-1 (reads hc, barrier-safe)
        if (t > 0) {
            const unsigned short* hp = hc + erow * LDH + epart * 32;
            const unsigned short* wp = wms_lds + (ekind * 2 + ec) * 128 + epart * 32;
            float s = 0.f;
#pragma unroll
            for (int j = 0; j < 4; j++) {
                short8 hv = *(const short8*)(hp + j * 8);
                short8 wv = *(const short8*)(wp + j * 8);
#pragma unroll
                for (int e = 0; e < 8; e++)
                    s += bf2f((unsigned short)hv[e]) * bf2f((unsigned short)wv[e]);
            }
            s += __shfl_xor(s, 1);
            s += __shfl_xor(s, 2);
            if (epart == 0) {
                float val = s + ebias;
                if (ekind) val = __expf(0.5f * val);
                out[(ekind ? STD_OFF : MUS_OFF) + ((size_t)(t - 1) * NB + b0 + erow) * 2 + ec] = val;
            }
        }

        // ---- gh MFMA over K=160 (kt4 frags from L2 each step; keeps regs lean)
        floatx4 acc[2][3];
#pragma unroll
        for (int mt = 0; mt < 2; mt++)
#pragma unroll
            for (int g = 0; g < 3; g++) acc[mt][g] = (floatx4){0.f, 0.f, 0.f, 0.f};
#pragma unroll
        for (int kt = 0; kt < 4; kt++) {
            short8 af2[2];
#pragma unroll
            for (int mt = 0; mt < 2; mt++)
                af2[mt] = *(const short8*)(hc + (mt * 16 + col) * LDH + kt * 32 + q * 8);
#pragma unroll
            for (int mt = 0; mt < 2; mt++)
#pragma unroll
                for (int g = 0; g < 3; g++)
                    acc[mt][g] = __builtin_amdgcn_mfma_f32_16x16x32_bf16(
                        af2[mt], bfr[g][kt], acc[mt][g], 0, 0, 0);
        }
        {
            short8 af4[2], k4f[3];
#pragma unroll
            for (int g = 0; g < 3; g++)
                k4f[g] = *(const short8*)(Whh + (size_t)(g * HH + jc) * 160 + 128 + q * 8);
#pragma unroll
            for (int mt = 0; mt < 2; mt++)
                af4[mt] = *(const short8*)(hc + (mt * 16 + col) * LDH + 128 + q * 8);
#pragma unroll
            for (int mt = 0; mt < 2; mt++)
#pragma unroll
                for (int g = 0; g < 3; g++)
                    acc[mt][g] = __builtin_amdgcn_mfma_f32_16x16x32_bf16(
                        af4[mt], k4f[g], acc[mt][g], 0, 0, 0);
        }

        // ---- gates (+n-gate a-term in VALU) + write h_{t+1}
#pragma unroll
        for (int mt = 0; mt < 2; mt++) {
#pragma unroll
            for (int r = 0; r < 4; r++) {
                int row = mt * 16 + q * 4 + r;
                unsigned int ap = *(const unsigned int*)(hc + row * LDH + 128);
                float a0v = upk(ap, 0), a1v = upk(ap, 1);
                float gir = upk(gp[mt][0][r >> 1], r & 1) + acc[mt][0][r];
                float giz = upk(gp[mt][1][r >> 1], r & 1) + acc[mt][1][r];
                float gin = upk(gp[mt][2][r >> 1], r & 1) + a0v * wan0 + a1v * wan1;
                float ghn = acc[mt][2][r];  // includes b_hh_n via K-slot 130
                float rg = fsig(gir);
                float zg = fsig(giz);
                float ng = ftanh(gin + rg * ghn);
                hprev[mt][r] = (1.f - zg) * ng + zg * hprev[mt][r];
                hn[row * LDH + jc] = f2bf(hprev[mt][r]);
            }
        }
        // stage a_{t+1} into hn ext slots (teacher forcing: fut[t,:,2:4])
        if (tid >= 448) {
            int i = tid - 448, row = i >> 1, c = i & 1;
            hn[row * LDH + 128 + c] = f2bf(fut[((size_t)t * NB + b0 + row) * 6 + 2 + c]);
        }
        __syncthreads();
    }

    // final mu/std for h_24 (lives in buf 0) -> out row 23
    {
        const unsigned short* hc = h2;  // (TT & 1) == 0
        const unsigned short* hp = hc + erow * LDH + epart * 32;
        const unsigned short* wp = wms_lds + (ekind * 2 + ec) * 128 + epart * 32;
        float s = 0.f;
#pragma unroll
        for (int j = 0; j < 4; j++) {
            short8 hv = *(const short8*)(hp + j * 8);
            short8 wv = *(const short8*)(wp + j * 8);
#pragma unroll
            for (int e = 0; e < 8; e++)
                s += bf2f((unsigned short)hv[e]) * bf2f((unsigned short)wv[e]);
        }
        s += __shfl_xor(s, 1);
        s += __shfl_xor(s, 2);
        if (epart == 0) {
            float val = s + ebias;
            if (ekind) val = __expf(0.5f * val);
            out[(ekind ? STD_OFF : MUS_OFF) + ((size_t)(TT - 1) * NB + b0 + erow) * 2 + ec] = val;
        }
    }
}

extern "C" void kernel_launch(void* const* d_in, const int* in_sizes, int n_in,
                              void* d_out, int out_size, void* d_ws, size_t ws_size,
                              hipStream_t stream) {
    (void)in_sizes; (void)n_in; (void)out_size; (void)ws_size;
    const float* last  = (const float*)d_in[0];
    const float* enc   = (const float*)d_in[1];
    const float* zin   = (const float*)d_in[2];
    const float* sg    = (const float*)d_in[3];
    const float* fut   = (const float*)d_in[4];
    const float* b_dh  = (const float*)d_in[6];
    const float* W_vel = (const float*)d_in[7];
    const float* b_vel = (const float*)d_in[8];
    const float* W_ih  = (const float*)d_in[9];
    const float* b_ih  = (const float*)d_in[10];
    const float* W_hh  = (const float*)d_in[11];
    const float* b_hh  = (const float*)d_in[12];
    const float* W_mu  = (const float*)d_in[13];
    const float* b_mu  = (const float*)d_in[14];
    const float* W_std = (const float*)d_in[15];
    const float* b_std = (const float*)d_in[16];
    const float* W_dh  = (const float*)d_in[5];
    float* out = (float*)d_out;

    char* ws = (char*)d_ws;
    unsigned short* Wc  = (unsigned short*)ws;              // 512*1056*2 = 1,081,344 B
    unsigned short* Whh = (unsigned short*)(ws + 1081344);  // 384*160*2  =   122,880 B
    unsigned short* Wms = (unsigned short*)(ws + 1204224);  // 4*128*2    =     1,024 B

    k_prep<<<897, 256, 0, stream>>>(W_ih, W_dh, W_hh, b_hh, W_mu, W_std, Wc, Whh, Wms);
    k_fused<<<512, 512, 0, stream>>>(last, enc, zin, sg, fut, b_dh, W_vel, b_vel,
                                     W_ih, b_ih, b_hh, b_mu, b_std, Wc, Whh, Wms, out);
}